// Round 9
// baseline (511.074 us; speedup 1.0000x reference)
//
#include <hip/hip_runtime.h>
#include <math.h>
#include <stdint.h>

#define SEQ 4096
#define DIM 1024
#define NB  4
#define NTILE 32              // 4096/128 M-tiles per batch
#define TRI  528              // NTILE*(NTILE+1)/2 packed causal tiles

typedef __attribute__((ext_vector_type(8))) __bf16 bf16x8;
typedef __attribute__((ext_vector_type(4))) float  f32x4;
typedef __attribute__((ext_vector_type(4))) float  floatx4;
typedef __attribute__((ext_vector_type(8))) unsigned short ushortx8;
typedef __attribute__((ext_vector_type(4))) unsigned short ushortx4;

__device__ __forceinline__ unsigned short f2bf(float f){
  union { float f; unsigned int u; } c; c.f = f;
  unsigned int u = c.u;
  return (unsigned short)((u + 0x7fffu + ((u >> 16) & 1u)) >> 16);
}

__device__ __forceinline__ f32x4 mfma16(bf16x8 a, bf16x8 b, f32x4 c){
  return __builtin_amdgcn_mfma_f32_16x16x32_bf16(a, b, c, 0, 0, 0);
}

__device__ __forceinline__ void g2l16(void* lds, const void* g){
  __builtin_amdgcn_global_load_lds(
      (const __attribute__((address_space(1))) unsigned int*)g,
      (__attribute__((address_space(3))) unsigned int*)lds, 16, 0, 0);
}

#define WAITVM0 asm volatile("s_waitcnt vmcnt(0)" ::: "memory")

// shared 128x128-tile MFMA inner step (uses acc, wr, wc, lr, lk from scope)
#define COMPUTE128(Asrc, Bsrc) do { \
  _Pragma("unroll") \
  for (int _ks = 0; _ks < 2; ++_ks){ \
    bf16x8 _af[4], _bf[4]; \
    _Pragma("unroll") \
    for (int _i = 0; _i < 4; ++_i){ \
      _af[_i] = *(const bf16x8*)&Asrc[wr + _i*16 + lr][_ks*32 + lk*8]; \
      _bf[_i] = *(const bf16x8*)&Bsrc[wc + _i*16 + lr][_ks*32 + lk*8]; \
    } \
    _Pragma("unroll") \
    for (int _i = 0; _i < 4; ++_i) \
      _Pragma("unroll") \
      for (int _j = 0; _j < 4; ++_j) \
        acc[_i][_j] = mfma16(_af[_i], _bf[_j], acc[_i][_j]); \
  } \
} while (0)

// ---------------- fp32 -> bf16 conversion ----------------
__global__ void cvt_kernel(const float* __restrict__ src,
                           unsigned short* __restrict__ dst, int n4){
  int i = blockIdx.x * blockDim.x + threadIdx.x;
  if (i >= n4) return;
  floatx4 v = *((const floatx4*)src + i);
  ushortx4 o;
  o[0] = f2bf(v[0]); o[1] = f2bf(v[1]); o[2] = f2bf(v[2]); o[3] = f2bf(v[3]);
  *((ushortx4*)dst + i) = o;
}

// ---------------- QKV projection GEMM (double-buffered 2-phase) ----------------
__global__ __launch_bounds__(256, 2) void gemm_qkv(
    const unsigned short* __restrict__ E,
    const unsigned short* __restrict__ W3,
    unsigned short* __restrict__ Qd,
    unsigned short* __restrict__ Kd,
    unsigned short* __restrict__ Vd)
{
  __shared__ unsigned short As[2][128][64];
  __shared__ unsigned short Bs[2][128][64];

  const int t  = threadIdx.x;
  const int m0 = blockIdx.y * 128;
  const int n0 = blockIdx.x * 128;
  const unsigned short* W = W3 + (size_t)blockIdx.z * (DIM * (size_t)DIM);
  unsigned short* dst = blockIdx.z == 0 ? Qd : (blockIdx.z == 1 ? Kd : Vd);

  const int l  = t & 63;
  const int w  = t >> 6;
  const int lr = l & 15;
  const int lk = l >> 4;
  const int wr = (w >> 1) * 64;
  const int wc = (w & 1) * 64;

#define QKV_STAGE(buf, kt) do { \
  const int _k0 = (kt) * 64; \
  _Pragma("unroll") \
  for (int _c = 0; _c < 4; ++_c){ \
    int _id  = _c * 256 + t; \
    int _row = _id >> 3; \
    int _cb  = (_id & 7) * 8; \
    g2l16(&As[buf][_row][_cb], E + (size_t)(m0 + _row) * DIM + _k0 + _cb); \
    g2l16(&Bs[buf][_row][_cb], W + (size_t)(n0 + _row) * DIM + _k0 + _cb); \
  } \
} while (0)

  f32x4 acc[4][4];
  #pragma unroll
  for (int i = 0; i < 4; ++i)
    #pragma unroll
    for (int j = 0; j < 4; ++j) acc[i][j] = (f32x4)0.0f;

  QKV_STAGE(0, 0);
  WAITVM0;
  __syncthreads();

  for (int kt = 0; kt < DIM / 64; kt += 2){
    QKV_STAGE(1, kt + 1);
    COMPUTE128(As[0], Bs[0]);
    WAITVM0;
    __syncthreads();
    if (kt + 2 < DIM / 64) QKV_STAGE(0, kt + 2);
    COMPUTE128(As[1], Bs[1]);
    WAITVM0;
    __syncthreads();
  }
#undef QKV_STAGE

  #pragma unroll
  for (int i = 0; i < 4; ++i)
    #pragma unroll
    for (int j = 0; j < 4; ++j)
      #pragma unroll
      for (int r = 0; r < 4; ++r){
        int row = wr + i*16 + lk*4 + r;
        int col = wc + j*16 + lr;
        dst[(size_t)(m0 + row) * DIM + n0 + col] = f2bf(acc[i][j][r]);
      }
}

// ---------------- V transpose ----------------
__global__ __launch_bounds__(256) void transpose_v(
    const unsigned short* __restrict__ V, unsigned short* __restrict__ VT)
{
  __shared__ unsigned short T[64][72];
  const int b  = blockIdx.z;
  const int s0 = blockIdx.x * 64;
  const int a0 = blockIdx.y * 64;
  const unsigned short* Vb = V + (size_t)b * SEQ * DIM;
  unsigned short* VTb = VT + (size_t)b * DIM * SEQ;
  const int t = threadIdx.x;
  const int r = t >> 3, cg = t & 7;
  #pragma unroll
  for (int p = 0; p < 2; ++p){
    int row = r + p * 32;
    ushortx8 v = *(const ushortx8*)(Vb + (size_t)(s0 + row) * DIM + a0 + cg*8);
    *(ushortx8*)&T[row][cg*8] = v;
  }
  __syncthreads();
  #pragma unroll
  for (int p = 0; p < 2; ++p){
    int ar = r + p * 32;
    ushortx8 o;
    #pragma unroll
    for (int j = 0; j < 8; ++j) o[j] = T[cg*8 + j][ar];
    *(ushortx8*)(VTb + (size_t)(a0 + ar) * SEQ + s0 + cg*8) = o;
  }
}

// ---------------- S/P GEMM: P = exp(scale * Q K^T) (causal), packed tiles ----
__global__ __launch_bounds__(256, 2) void sp_gemm(
    const unsigned short* __restrict__ Q,
    const unsigned short* __restrict__ K,
    unsigned short* __restrict__ Sp,
    float* __restrict__ lrow)
{
  const int tj = blockIdx.x;
  const int ti = blockIdx.y;
  if (tj > ti) return;
  const int b  = blockIdx.z;

  __shared__ unsigned short As[2][128][64];
  __shared__ unsigned short Bs[2][128][64];

  const int t  = threadIdx.x;
  const int m0 = ti * 128;
  const int n0 = tj * 128;
  const unsigned short* A = Q + (size_t)b * SEQ * DIM;
  const unsigned short* B = K + (size_t)b * SEQ * DIM;

  const int l  = t & 63;
  const int w  = t >> 6;
  const int lr = l & 15;
  const int lk = l >> 4;
  const int wr = (w >> 1) * 64;
  const int wc = (w & 1) * 64;

#define SP_STAGE(buf, kt) do { \
  const int _k0 = (kt) * 64; \
  _Pragma("unroll") \
  for (int _c = 0; _c < 4; ++_c){ \
    int _id  = _c * 256 + t; \
    int _row = _id >> 3; \
    int _cb  = (_id & 7) * 8; \
    g2l16(&As[buf][_row][_cb], A + (size_t)(m0 + _row) * DIM + _k0 + _cb); \
    g2l16(&Bs[buf][_row][_cb], B + (size_t)(n0 + _row) * DIM + _k0 + _cb); \
  } \
} while (0)

  f32x4 acc[4][4];
  #pragma unroll
  for (int i = 0; i < 4; ++i)
    #pragma unroll
    for (int j = 0; j < 4; ++j) acc[i][j] = (f32x4)0.0f;

  SP_STAGE(0, 0);
  WAITVM0;
  __syncthreads();

  for (int kt = 0; kt < DIM / 64; kt += 2){
    SP_STAGE(1, kt + 1);
    COMPUTE128(As[0], Bs[0]);
    WAITVM0;
    __syncthreads();
    if (kt + 2 < DIM / 64) SP_STAGE(0, kt + 2);
    COMPUTE128(As[1], Bs[1]);
    WAITVM0;
    __syncthreads();
  }
#undef SP_STAGE

  // epilogue: P = exp(scale*acc) masked; bf16 packed write; row-sum atomics
  const float scale = 0.03125f;  // 1/sqrt(1024)
  unsigned short* tile =
      Sp + ((size_t)b * TRI + (size_t)(ti * (ti + 1) / 2) + tj) * 16384;
  float* lb = lrow + (size_t)b * SEQ + m0;

  #pragma unroll
  for (int i = 0; i < 4; ++i){
    float rs[4] = {0.f, 0.f, 0.f, 0.f};
    #pragma unroll
    for (int j = 0; j < 4; ++j){
      #pragma unroll
      for (int r = 0; r < 4; ++r){
        int row = wr + i*16 + lk*4 + r;
        int col = wc + j*16 + lr;
        float p = 0.0f;
        if (n0 + col <= m0 + row) p = __expf(acc[i][j][r] * scale);
        rs[r] += p;
        tile[row * 128 + col] = f2bf(p);
      }
    }
    #pragma unroll
    for (int r = 0; r < 4; ++r){
      float v = rs[r];
      v += __shfl_xor(v, 1, 64);
      v += __shfl_xor(v, 2, 64);
      v += __shfl_xor(v, 4, 64);
      v += __shfl_xor(v, 8, 64);
      if (lr == 0)
        atomicAdd(&lb[wr + i*16 + lk*4 + r], v);
    }
  }
}

// ---------------- PV GEMM: O = (P V) / l. A = packed P, B = VT ----------------
__global__ __launch_bounds__(256, 2) void pv_gemm(
    const unsigned short* __restrict__ Sp,
    const unsigned short* __restrict__ VT,
    const float* __restrict__ lrow,
    float* __restrict__ out)
{
  __shared__ unsigned short As[2][128][64];
  __shared__ unsigned short Bs[2][128][64];

  const int nx = blockIdx.x;
  const int pr = blockIdx.y;
  const int b  = blockIdx.z;
  const int t  = threadIdx.x;

  const int l  = t & 63;
  const int w  = t >> 6;
  const int lr = l & 15;
  const int lk = l >> 4;
  const int wr = (w >> 1) * 64;
  const int wc = (w & 1) * 64;

  const int n0 = nx * 128;
  const unsigned short* VTb = VT + (size_t)b * DIM * SEQ;
  const unsigned short* Spb = Sp + (size_t)b * TRI * 16384;

  for (int half = 0; half < 2; ++half){
    const int ti = half ? pr : (31 - pr);
    const int m0 = ti * 128;
    const unsigned short* Pt = Spb + (size_t)(ti * (ti + 1) / 2) * 16384;
    const int ksteps = 2 * (ti + 1);   // always even

#define PV_STAGE(buf, s) do { \
  _Pragma("unroll") \
  for (int _c = 0; _c < 4; ++_c){ \
    int _id  = _c * 256 + t; \
    int _row = _id >> 3; \
    int _cb  = (_id & 7) * 8; \
    g2l16(&As[buf][_row][_cb], \
          Pt + (size_t)((s) >> 1) * 16384 + _row * 128 + ((s) & 1) * 64 + _cb); \
    g2l16(&Bs[buf][_row][_cb], \
          VTb + (size_t)(n0 + _row) * SEQ + (s) * 64 + _cb); \
  } \
} while (0)

    f32x4 acc[4][4];
    #pragma unroll
    for (int i = 0; i < 4; ++i)
      #pragma unroll
      for (int j = 0; j < 4; ++j) acc[i][j] = (f32x4)0.0f;

    PV_STAGE(0, 0);
    WAITVM0;
    __syncthreads();

    for (int s = 0; s < ksteps; s += 2){
      PV_STAGE(1, s + 1);
      COMPUTE128(As[0], Bs[0]);
      WAITVM0;
      __syncthreads();
      if (s + 2 < ksteps) PV_STAGE(0, s + 2);
      COMPUTE128(As[1], Bs[1]);
      WAITVM0;
      __syncthreads();
    }
#undef PV_STAGE

    const float* lb = lrow + (size_t)b * SEQ + m0;
    float* ob = out + ((size_t)b * SEQ + m0) * DIM + n0;
    #pragma unroll
    for (int i = 0; i < 4; ++i)
      #pragma unroll
      for (int r = 0; r < 4; ++r){
        int row = wr + i*16 + lk*4 + r;
        float inv = 1.0f / lb[row];
        #pragma unroll
        for (int j = 0; j < 4; ++j)
          ob[(size_t)row * DIM + wc + j*16 + lr] = acc[i][j][r] * inv;
      }
  }
}

// ---------------- launch ----------------
extern "C" void kernel_launch(void* const* d_in, const int* in_sizes, int n_in,
                              void* d_out, int out_size, void* d_ws, size_t ws_size,
                              hipStream_t stream)
{
  (void)in_sizes; (void)n_in; (void)out_size; (void)ws_size;
  const float* emb = (const float*)d_in[0];
  const float* Wq  = (const float*)d_in[1];
  const float* Wk  = (const float*)d_in[2];
  const float* Wv  = (const float*)d_in[3];

  char* ws = (char*)d_ws;
  unsigned short* EB = (unsigned short*)ws;                    // 32MB (reused as VT)
  unsigned short* WB = (unsigned short*)(ws + 33554432);       // 6MB: Wq|Wk|Wv bf16
  unsigned short* Qb = (unsigned short*)(ws + 39845888);       // 32MB
  unsigned short* Kb = (unsigned short*)(ws + 73400320);       // 32MB
  unsigned short* Sp = (unsigned short*)(ws + 106954752);      // 66MB packed P tiles
  float*          lr = (float*)(ws + 176160768);               // 64KB row sums
  unsigned short* Vb = (unsigned short*)d_out;                 // V scratch in out buffer
  unsigned short* VT = EB;                                     // alias: E dead after gemm

  hipMemsetAsync(lr, 0, (size_t)NB * SEQ * sizeof(float), stream);

  cvt_kernel<<<16384, 256, 0, stream>>>(emb, EB, 4194304);
  cvt_kernel<<<1024, 256, 0, stream>>>(Wq, WB,           262144);
  cvt_kernel<<<1024, 256, 0, stream>>>(Wk, WB + 1048576, 262144);
  cvt_kernel<<<1024, 256, 0, stream>>>(Wv, WB + 2097152, 262144);

  gemm_qkv<<<dim3(8, 128, 3), 256, 0, stream>>>(EB, WB, Qb, Kb, Vb);
  transpose_v<<<dim3(64, 16, 4), 256, 0, stream>>>(Vb, VT);

  sp_gemm<<<dim3(32, 32, 4), 256, 0, stream>>>(Qb, Kb, Sp, lr);
  pv_gemm<<<dim3(8, 16, 4), 256, 0, stream>>>(Sp, VT, lr, (float*)d_out);
}

// Round 10
// 495.669 us; speedup vs baseline: 1.0311x; 1.0311x over previous
//
#include <hip/hip_runtime.h>
#include <math.h>
#include <stdint.h>

#define SEQ 4096
#define DIM 1024
#define NB  4
#define NTILE 32              // 4096/128 M-tiles per batch
#define TRI  528              // NTILE*(NTILE+1)/2 packed causal tiles

typedef __attribute__((ext_vector_type(8))) __bf16 bf16x8;
typedef __attribute__((ext_vector_type(4))) float  f32x4;
typedef __attribute__((ext_vector_type(4))) float  floatx4;
typedef __attribute__((ext_vector_type(8))) unsigned short ushortx8;
typedef __attribute__((ext_vector_type(4))) unsigned short ushortx4;

__device__ __forceinline__ unsigned short f2bf(float f){
  union { float f; unsigned int u; } c; c.f = f;
  unsigned int u = c.u;
  return (unsigned short)((u + 0x7fffu + ((u >> 16) & 1u)) >> 16);
}

__device__ __forceinline__ f32x4 mfma16(bf16x8 a, bf16x8 b, f32x4 c){
  return __builtin_amdgcn_mfma_f32_16x16x32_bf16(a, b, c, 0, 0, 0);
}

__device__ __forceinline__ void g2l16(void* lds, const void* g){
  __builtin_amdgcn_global_load_lds(
      (const __attribute__((address_space(1))) unsigned int*)g,
      (__attribute__((address_space(3))) unsigned int*)lds, 16, 0, 0);
}

#define WAITVM8 asm volatile("s_waitcnt vmcnt(8)" ::: "memory")
#define WAITVM4 asm volatile("s_waitcnt vmcnt(4)" ::: "memory")
#define WAITVM0 asm volatile("s_waitcnt vmcnt(0)" ::: "memory")

// XOR swizzle: spreads 16 consecutive rows of a 64B-row tile across 8
// bank-quad positions (2-way conflict = free). Involution; 16B-granular.
#define SWZ(r) ((((r) ^ ((r) >> 2)) & 3) << 4)

// ---- pipelined K=1024 GEMM core: BK=32, 4-deep LDS rotation, vmcnt(8) ----
// Needs in scope: t, wr, wc, lr, lk16(=lk*16), Ab[4][128][32], Bb[4][128][32],
// Asrc/Bsrc (bf16 row-major, row stride 2048B), m0, n0. Defines acc[4][4].
#define STG(ktile) do { \
  const int _kt = (ktile); \
  const int _kb = _kt & 3; \
  const int _k0b = _kt * 64; \
  _Pragma("unroll") \
  for (int _c = 0; _c < 2; ++_c){ \
    int _id = _c * 256 + t; \
    int _r  = _id >> 2; \
    int _cb = (_id & 3) * 16; \
    g2l16((char*)&Ab[_kb][0][0] + (size_t)_id * 16, \
          (const char*)Asrc + (size_t)(m0 + _r) * 2048 + _k0b + (_cb ^ SWZ(_r))); \
    g2l16((char*)&Bb[_kb][0][0] + (size_t)_id * 16, \
          (const char*)Bsrc + (size_t)(n0 + _r) * 2048 + _k0b + (_cb ^ SWZ(_r))); \
  } \
} while (0)

#define GEMM_CORE_K1024() do { \
  STG(0); STG(1); STG(2); \
  WAITVM8; \
  __syncthreads(); \
  for (int kt = 0; kt < 32; ++kt){ \
    const int kb = kt & 3; \
    bf16x8 af[4], bfr[4]; \
    _Pragma("unroll") \
    for (int i = 0; i < 4; ++i){ \
      int ra = wr + i*16 + lr; \
      int rb = wc + i*16 + lr; \
      af[i]  = *(const bf16x8*)((const char*)&Ab[kb][ra][0] + (lk16 ^ SWZ(ra))); \
      bfr[i] = *(const bf16x8*)((const char*)&Bb[kb][rb][0] + (lk16 ^ SWZ(rb))); \
    } \
    if (kt < 29) STG(kt + 3); \
    if (kt < 29) { WAITVM8; } else if (kt == 29) { WAITVM4; } else { WAITVM0; } \
    __syncthreads(); \
    __builtin_amdgcn_s_setprio(1); \
    _Pragma("unroll") \
    for (int i = 0; i < 4; ++i) \
      _Pragma("unroll") \
      for (int j = 0; j < 4; ++j) \
        acc[i][j] = mfma16(af[i], bfr[j], acc[i][j]); \
    __builtin_amdgcn_s_setprio(0); \
    __syncthreads(); \
  } \
} while (0)

// ---------------- fp32 -> bf16 conversion ----------------
__global__ void cvt_kernel(const float* __restrict__ src,
                           unsigned short* __restrict__ dst, int n4){
  int i = blockIdx.x * blockDim.x + threadIdx.x;
  if (i >= n4) return;
  floatx4 v = *((const floatx4*)src + i);
  ushortx4 o;
  o[0] = f2bf(v[0]); o[1] = f2bf(v[1]); o[2] = f2bf(v[2]); o[3] = f2bf(v[3]);
  *((ushortx4*)dst + i) = o;
}

// ---------------- QKV projection GEMM (pipelined core) ----------------
__global__ __launch_bounds__(256, 2) void gemm_qkv(
    const unsigned short* __restrict__ E,
    const unsigned short* __restrict__ W3,
    unsigned short* __restrict__ Qd,
    unsigned short* __restrict__ Kd,
    unsigned short* __restrict__ Vd)
{
  __shared__ unsigned short Ab[4][128][32];
  __shared__ unsigned short Bb[4][128][32];

  const int t  = threadIdx.x;
  const int m0 = blockIdx.y * 128;
  const int n0 = blockIdx.x * 128;
  const unsigned short* Asrc = E;
  const unsigned short* Bsrc = W3 + (size_t)blockIdx.z * (DIM * (size_t)DIM);
  unsigned short* dst = blockIdx.z == 0 ? Qd : (blockIdx.z == 1 ? Kd : Vd);

  const int l  = t & 63;
  const int w  = t >> 6;
  const int lr = l & 15;
  const int lk = l >> 4;
  const int lk16 = lk * 16;
  const int wr = (w >> 1) * 64;
  const int wc = (w & 1) * 64;

  f32x4 acc[4][4];
  #pragma unroll
  for (int i = 0; i < 4; ++i)
    #pragma unroll
    for (int j = 0; j < 4; ++j) acc[i][j] = (f32x4)0.0f;

  GEMM_CORE_K1024();

  #pragma unroll
  for (int i = 0; i < 4; ++i)
    #pragma unroll
    for (int j = 0; j < 4; ++j)
      #pragma unroll
      for (int r = 0; r < 4; ++r){
        int row = wr + i*16 + lk*4 + r;
        int col = wc + j*16 + lr;
        dst[(size_t)(m0 + row) * DIM + n0 + col] = f2bf(acc[i][j][r]);
      }
}

// ---------------- V transpose ----------------
__global__ __launch_bounds__(256) void transpose_v(
    const unsigned short* __restrict__ V, unsigned short* __restrict__ VT)
{
  __shared__ unsigned short T[64][72];
  const int b  = blockIdx.z;
  const int s0 = blockIdx.x * 64;
  const int a0 = blockIdx.y * 64;
  const unsigned short* Vb = V + (size_t)b * SEQ * DIM;
  unsigned short* VTb = VT + (size_t)b * DIM * SEQ;
  const int t = threadIdx.x;
  const int r = t >> 3, cg = t & 7;
  #pragma unroll
  for (int p = 0; p < 2; ++p){
    int row = r + p * 32;
    ushortx8 v = *(const ushortx8*)(Vb + (size_t)(s0 + row) * DIM + a0 + cg*8);
    *(ushortx8*)&T[row][cg*8] = v;
  }
  __syncthreads();
  #pragma unroll
  for (int p = 0; p < 2; ++p){
    int ar = r + p * 32;
    ushortx8 o;
    #pragma unroll
    for (int j = 0; j < 8; ++j) o[j] = T[cg*8 + j][ar];
    *(ushortx8*)(VTb + (size_t)(a0 + ar) * SEQ + s0 + cg*8) = o;
  }
}

// ---------------- S/P GEMM: P = exp(scale * Q K^T) (causal), pipelined ----
__global__ __launch_bounds__(256, 2) void sp_gemm(
    const unsigned short* __restrict__ Q,
    const unsigned short* __restrict__ K,
    unsigned short* __restrict__ Sp,
    float* __restrict__ lrow)
{
  const int tj = blockIdx.x;
  const int ti = blockIdx.y;
  if (tj > ti) return;
  const int b  = blockIdx.z;

  __shared__ unsigned short Ab[4][128][32];
  __shared__ unsigned short Bb[4][128][32];

  const int t  = threadIdx.x;
  const int m0 = ti * 128;
  const int n0 = tj * 128;
  const unsigned short* Asrc = Q + (size_t)b * SEQ * DIM;
  const unsigned short* Bsrc = K + (size_t)b * SEQ * DIM;

  const int l  = t & 63;
  const int w  = t >> 6;
  const int lr = l & 15;
  const int lk = l >> 4;
  const int lk16 = lk * 16;
  const int wr = (w >> 1) * 64;
  const int wc = (w & 1) * 64;

  f32x4 acc[4][4];
  #pragma unroll
  for (int i = 0; i < 4; ++i)
    #pragma unroll
    for (int j = 0; j < 4; ++j) acc[i][j] = (f32x4)0.0f;

  GEMM_CORE_K1024();

  // epilogue: P = exp(scale*acc) masked; bf16 packed write; row-sum atomics
  const float scale = 0.03125f;  // 1/sqrt(1024)
  unsigned short* tile =
      Sp + ((size_t)b * TRI + (size_t)(ti * (ti + 1) / 2) + tj) * 16384;
  float* lb = lrow + (size_t)b * SEQ + m0;

  #pragma unroll
  for (int i = 0; i < 4; ++i){
    float rs[4] = {0.f, 0.f, 0.f, 0.f};
    #pragma unroll
    for (int j = 0; j < 4; ++j){
      #pragma unroll
      for (int r = 0; r < 4; ++r){
        int row = wr + i*16 + lk*4 + r;
        int col = wc + j*16 + lr;
        float p = 0.0f;
        if (n0 + col <= m0 + row) p = __expf(acc[i][j][r] * scale);
        rs[r] += p;
        tile[row * 128 + col] = f2bf(p);
      }
    }
    #pragma unroll
    for (int r = 0; r < 4; ++r){
      float v = rs[r];
      v += __shfl_xor(v, 1, 64);
      v += __shfl_xor(v, 2, 64);
      v += __shfl_xor(v, 4, 64);
      v += __shfl_xor(v, 8, 64);
      if (lr == 0)
        atomicAdd(&lb[wr + i*16 + lk*4 + r], v);
    }
  }
}

// ---------------- PV GEMM: O = (P V) / l. A = packed P, B = VT (r8 form) ----
__global__ __launch_bounds__(256, 2) void pv_gemm(
    const unsigned short* __restrict__ Sp,
    const unsigned short* __restrict__ VT,
    const float* __restrict__ lrow,
    float* __restrict__ out)
{
  __shared__ unsigned short As[128][64];
  __shared__ unsigned short Bs[128][64];

  const int nx = blockIdx.x;
  const int pr = blockIdx.y;
  const int b  = blockIdx.z;
  const int t  = threadIdx.x;

  const int l  = t & 63;
  const int w  = t >> 6;
  const int lr = l & 15;
  const int lk = l >> 4;
  const int wr = (w >> 1) * 64;
  const int wc = (w & 1) * 64;

  const int n0 = nx * 128;
  const unsigned short* VTb = VT + (size_t)b * DIM * SEQ;
  const unsigned short* Spb = Sp + (size_t)b * TRI * 16384;

  for (int half = 0; half < 2; ++half){
    const int ti = half ? pr : (31 - pr);
    const int m0 = ti * 128;
    const unsigned short* Pt = Spb + (size_t)(ti * (ti + 1) / 2) * 16384;
    const int ksteps = 2 * (ti + 1);

    f32x4 acc[4][4];
    #pragma unroll
    for (int i = 0; i < 4; ++i)
      #pragma unroll
      for (int j = 0; j < 4; ++j) acc[i][j] = (f32x4)0.0f;

    for (int s = 0; s < ksteps; ++s){
      #pragma unroll
      for (int c = 0; c < 4; ++c){
        int id  = c * 256 + t;
        int row = id >> 3;
        int cb  = (id & 7) * 8;
        g2l16(&As[row][cb],
              Pt + (size_t)(s >> 1) * 16384 + row * 128 + (s & 1) * 64 + cb);
        g2l16(&Bs[row][cb],
              VTb + (size_t)(n0 + row) * SEQ + s * 64 + cb);
      }
      WAITVM0;
      __syncthreads();
      #pragma unroll
      for (int ks = 0; ks < 2; ++ks){
        bf16x8 af[4], bfr[4];
        #pragma unroll
        for (int i = 0; i < 4; ++i){
          af[i]  = *(const bf16x8*)&As[wr + i*16 + lr][ks*32 + lk*8];
          bfr[i] = *(const bf16x8*)&Bs[wc + i*16 + lr][ks*32 + lk*8];
        }
        #pragma unroll
        for (int i = 0; i < 4; ++i)
          #pragma unroll
          for (int j = 0; j < 4; ++j)
            acc[i][j] = mfma16(af[i], bfr[j], acc[i][j]);
      }
      __syncthreads();
    }

    const float* lb = lrow + (size_t)b * SEQ + m0;
    float* ob = out + ((size_t)b * SEQ + m0) * DIM + n0;
    #pragma unroll
    for (int i = 0; i < 4; ++i)
      #pragma unroll
      for (int r = 0; r < 4; ++r){
        int row = wr + i*16 + lk*4 + r;
        float inv = 1.0f / lb[row];
        #pragma unroll
        for (int j = 0; j < 4; ++j)
          ob[(size_t)row * DIM + wc + j*16 + lr] = acc[i][j][r] * inv;
      }
  }
}

// ---------------- launch ----------------
extern "C" void kernel_launch(void* const* d_in, const int* in_sizes, int n_in,
                              void* d_out, int out_size, void* d_ws, size_t ws_size,
                              hipStream_t stream)
{
  (void)in_sizes; (void)n_in; (void)out_size; (void)ws_size;
  const float* emb = (const float*)d_in[0];
  const float* Wq  = (const float*)d_in[1];
  const float* Wk  = (const float*)d_in[2];
  const float* Wv  = (const float*)d_in[3];

  char* ws = (char*)d_ws;
  unsigned short* EB = (unsigned short*)ws;                    // 32MB (reused as VT)
  unsigned short* WB = (unsigned short*)(ws + 33554432);       // 6MB: Wq|Wk|Wv bf16
  unsigned short* Qb = (unsigned short*)(ws + 39845888);       // 32MB
  unsigned short* Kb = (unsigned short*)(ws + 73400320);       // 32MB
  unsigned short* Sp = (unsigned short*)(ws + 106954752);      // 66MB packed P tiles
  float*          lr = (float*)(ws + 176160768);               // 64KB row sums
  unsigned short* Vb = (unsigned short*)d_out;                 // V scratch in out buffer
  unsigned short* VT = EB;                                     // alias: E dead after gemm

  hipMemsetAsync(lr, 0, (size_t)NB * SEQ * sizeof(float), stream);

  cvt_kernel<<<16384, 256, 0, stream>>>(emb, EB, 4194304);
  cvt_kernel<<<1024, 256, 0, stream>>>(Wq, WB,           262144);
  cvt_kernel<<<1024, 256, 0, stream>>>(Wk, WB + 1048576, 262144);
  cvt_kernel<<<1024, 256, 0, stream>>>(Wv, WB + 2097152, 262144);

  gemm_qkv<<<dim3(8, 128, 3), 256, 0, stream>>>(EB, WB, Qb, Kb, Vb);
  transpose_v<<<dim3(64, 16, 4), 256, 0, stream>>>(Vb, VT);

  sp_gemm<<<dim3(32, 32, 4), 256, 0, stream>>>(Qb, Kb, Sp, lr);
  pv_gemm<<<dim3(8, 16, 4), 256, 0, stream>>>(Sp, VT, lr, (float*)d_out);
}

// Round 11
// 388.121 us; speedup vs baseline: 1.3168x; 1.2771x over previous
//
#include <hip/hip_runtime.h>
#include <math.h>
#include <stdint.h>

#define SEQ 4096
#define DIM 1024
#define NB  4
#define NTILE 32              // 4096/128 M-tiles per batch
#define TRI  528              // NTILE*(NTILE+1)/2 packed causal tiles

typedef __attribute__((ext_vector_type(8))) __bf16 bf16x8;
typedef __attribute__((ext_vector_type(4))) float  f32x4;
typedef __attribute__((ext_vector_type(4))) float  floatx4;
typedef __attribute__((ext_vector_type(8))) unsigned short ushortx8;
typedef __attribute__((ext_vector_type(4))) unsigned short ushortx4;

__device__ __forceinline__ unsigned short f2bf(float f){
  union { float f; unsigned int u; } c; c.f = f;
  unsigned int u = c.u;
  return (unsigned short)((u + 0x7fffu + ((u >> 16) & 1u)) >> 16);
}

__device__ __forceinline__ f32x4 mfma16(bf16x8 a, bf16x8 b, f32x4 c){
  return __builtin_amdgcn_mfma_f32_16x16x32_bf16(a, b, c, 0, 0, 0);
}

__device__ __forceinline__ void g2l16(void* lds, const void* g){
  __builtin_amdgcn_global_load_lds(
      (const __attribute__((address_space(1))) unsigned int*)g,
      (__attribute__((address_space(3))) unsigned int*)lds, 16, 0, 0);
}

#define WAITVM0 asm volatile("s_waitcnt vmcnt(0)" ::: "memory")

// T2 XOR swizzle, 16B granularity: row r's 128B line is rotated by (r&7)*16B.
// 16 consecutive rows -> 8 distinct 16B slots -> 2-way bank aliasing (free).
#define SWZB(r) (((r) & 7) << 4)

// stage one 128x64 bf16 tile (linear LDS dest, pre-swizzled global source)
// Aptr/Bptr = byte pointers to the tile corner; strides in bytes.
#define STAGE_AB(Aptr, Astr, Bptr, Bstr) do { \
  _Pragma("unroll") \
  for (int _c = 0; _c < 4; ++_c){ \
    int _id  = _c * 256 + t; \
    int _row = _id >> 3; \
    int _sw  = ((_id & 7) * 16) ^ SWZB(_row); \
    g2l16((char*)As + (size_t)_id * 16, \
          (const char*)(Aptr) + (size_t)_row * (Astr) + _sw); \
    g2l16((char*)Bs + (size_t)_id * 16, \
          (const char*)(Bptr) + (size_t)_row * (Bstr) + _sw); \
  } \
} while (0)

// 128x128-tile MFMA step over one staged 64-K slab (swizzled ds_reads)
#define COMPUTE128S() do { \
  _Pragma("unroll") \
  for (int _ks = 0; _ks < 2; ++_ks){ \
    bf16x8 _af[4], _bf[4]; \
    _Pragma("unroll") \
    for (int _i = 0; _i < 4; ++_i){ \
      int _ra = wr + _i*16 + lr; \
      int _rb = wc + _i*16 + lr; \
      _af[_i] = *(const bf16x8*)((const char*)As + (size_t)_ra * 128 \
                                 + ((_ks*64 + lk16) ^ SWZB(_ra))); \
      _bf[_i] = *(const bf16x8*)((const char*)Bs + (size_t)_rb * 128 \
                                 + ((_ks*64 + lk16) ^ SWZB(_rb))); \
    } \
    __builtin_amdgcn_s_setprio(1); \
    _Pragma("unroll") \
    for (int _i = 0; _i < 4; ++_i) \
      _Pragma("unroll") \
      for (int _j = 0; _j < 4; ++_j) \
        acc[_i][_j] = mfma16(_af[_i], _bf[_j], acc[_i][_j]); \
    __builtin_amdgcn_s_setprio(0); \
  } \
} while (0)

// ---------------- fp32 -> bf16 conversion ----------------
__global__ void cvt_kernel(const float* __restrict__ src,
                           unsigned short* __restrict__ dst, int n4){
  int i = blockIdx.x * blockDim.x + threadIdx.x;
  if (i >= n4) return;
  floatx4 v = *((const floatx4*)src + i);
  ushortx4 o;
  o[0] = f2bf(v[0]); o[1] = f2bf(v[1]); o[2] = f2bf(v[2]); o[3] = f2bf(v[3]);
  *((ushortx4*)dst + i) = o;
}

// ---------------- QKV projection GEMM (r8 structure + swizzle) ----------------
__global__ __launch_bounds__(256, 2) void gemm_qkv(
    const unsigned short* __restrict__ E,
    const unsigned short* __restrict__ W3,
    unsigned short* __restrict__ Qd,
    unsigned short* __restrict__ Kd,
    unsigned short* __restrict__ Vd)
{
  __shared__ unsigned short As[128 * 64];
  __shared__ unsigned short Bs[128 * 64];

  const int t  = threadIdx.x;
  const int m0 = blockIdx.y * 128;
  const int n0 = blockIdx.x * 128;
  const unsigned short* W = W3 + (size_t)blockIdx.z * (DIM * (size_t)DIM);
  unsigned short* dst = blockIdx.z == 0 ? Qd : (blockIdx.z == 1 ? Kd : Vd);

  const int l  = t & 63;
  const int w  = t >> 6;
  const int lr = l & 15;
  const int lk = l >> 4;
  const int lk16 = lk * 16;
  const int wr = (w >> 1) * 64;
  const int wc = (w & 1) * 64;

  const char* Abase = (const char*)E + (size_t)m0 * 2048;
  const char* Bbase = (const char*)W + (size_t)n0 * 2048;

  f32x4 acc[4][4];
  #pragma unroll
  for (int i = 0; i < 4; ++i)
    #pragma unroll
    for (int j = 0; j < 4; ++j) acc[i][j] = (f32x4)0.0f;

  for (int kt = 0; kt < DIM / 64; ++kt){
    STAGE_AB(Abase + kt * 128, 2048, Bbase + kt * 128, 2048);
    WAITVM0;
    __syncthreads();
    COMPUTE128S();
    __syncthreads();
  }

  #pragma unroll
  for (int i = 0; i < 4; ++i)
    #pragma unroll
    for (int j = 0; j < 4; ++j)
      #pragma unroll
      for (int r = 0; r < 4; ++r){
        int row = wr + i*16 + lk*4 + r;
        int col = wc + j*16 + lr;
        dst[(size_t)(m0 + row) * DIM + n0 + col] = f2bf(acc[i][j][r]);
      }
}

// ---------------- V transpose ----------------
__global__ __launch_bounds__(256) void transpose_v(
    const unsigned short* __restrict__ V, unsigned short* __restrict__ VT)
{
  __shared__ unsigned short T[64][72];
  const int b  = blockIdx.z;
  const int s0 = blockIdx.x * 64;
  const int a0 = blockIdx.y * 64;
  const unsigned short* Vb = V + (size_t)b * SEQ * DIM;
  unsigned short* VTb = VT + (size_t)b * DIM * SEQ;
  const int t = threadIdx.x;
  const int r = t >> 3, cg = t & 7;
  #pragma unroll
  for (int p = 0; p < 2; ++p){
    int row = r + p * 32;
    ushortx8 v = *(const ushortx8*)(Vb + (size_t)(s0 + row) * DIM + a0 + cg*8);
    *(ushortx8*)&T[row][cg*8] = v;
  }
  __syncthreads();
  #pragma unroll
  for (int p = 0; p < 2; ++p){
    int ar = r + p * 32;
    ushortx8 o;
    #pragma unroll
    for (int j = 0; j < 8; ++j) o[j] = T[cg*8 + j][ar];
    *(ushortx8*)(VTb + (size_t)(a0 + ar) * SEQ + s0 + cg*8) = o;
  }
}

// ---------------- S/P GEMM: P = exp(scale * Q K^T) (causal) ----------------
__global__ __launch_bounds__(256, 2) void sp_gemm(
    const unsigned short* __restrict__ Q,
    const unsigned short* __restrict__ K,
    unsigned short* __restrict__ Sp,
    float* __restrict__ lrow)
{
  const int tj = blockIdx.x;
  const int ti = blockIdx.y;
  if (tj > ti) return;
  const int b  = blockIdx.z;

  __shared__ unsigned short As[128 * 64];
  __shared__ unsigned short Bs[128 * 64];

  const int t  = threadIdx.x;
  const int m0 = ti * 128;
  const int n0 = tj * 128;

  const int l  = t & 63;
  const int w  = t >> 6;
  const int lr = l & 15;
  const int lk = l >> 4;
  const int lk16 = lk * 16;
  const int wr = (w >> 1) * 64;
  const int wc = (w & 1) * 64;

  const char* Abase = (const char*)(Q + (size_t)b * SEQ * DIM) + (size_t)m0 * 2048;
  const char* Bbase = (const char*)(K + (size_t)b * SEQ * DIM) + (size_t)n0 * 2048;

  f32x4 acc[4][4];
  #pragma unroll
  for (int i = 0; i < 4; ++i)
    #pragma unroll
    for (int j = 0; j < 4; ++j) acc[i][j] = (f32x4)0.0f;

  for (int kt = 0; kt < DIM / 64; ++kt){
    STAGE_AB(Abase + kt * 128, 2048, Bbase + kt * 128, 2048);
    WAITVM0;
    __syncthreads();
    COMPUTE128S();
    __syncthreads();
  }

  // epilogue: P = exp(scale*acc) masked; bf16 packed write; row-sum atomics
  const float scale = 0.03125f;  // 1/sqrt(1024)
  unsigned short* tile =
      Sp + ((size_t)b * TRI + (size_t)(ti * (ti + 1) / 2) + tj) * 16384;
  float* lb = lrow + (size_t)b * SEQ + m0;

  #pragma unroll
  for (int i = 0; i < 4; ++i){
    float rs[4] = {0.f, 0.f, 0.f, 0.f};
    #pragma unroll
    for (int j = 0; j < 4; ++j){
      #pragma unroll
      for (int r = 0; r < 4; ++r){
        int row = wr + i*16 + lk*4 + r;
        int col = wc + j*16 + lr;
        float p = 0.0f;
        if (n0 + col <= m0 + row) p = __expf(acc[i][j][r] * scale);
        rs[r] += p;
        tile[row * 128 + col] = f2bf(p);
      }
    }
    #pragma unroll
    for (int r = 0; r < 4; ++r){
      float v = rs[r];
      v += __shfl_xor(v, 1, 64);
      v += __shfl_xor(v, 2, 64);
      v += __shfl_xor(v, 4, 64);
      v += __shfl_xor(v, 8, 64);
      if (lr == 0)
        atomicAdd(&lb[wr + i*16 + lk*4 + r], v);
    }
  }
}

// ---------------- PV GEMM: O = (P V) / l. A = packed P, B = VT ----------------
__global__ __launch_bounds__(256, 2) void pv_gemm(
    const unsigned short* __restrict__ Sp,
    const unsigned short* __restrict__ VT,
    const float* __restrict__ lrow,
    float* __restrict__ out)
{
  __shared__ unsigned short As[128 * 64];
  __shared__ unsigned short Bs[128 * 64];

  const int nx = blockIdx.x;
  const int pr = blockIdx.y;
  const int b  = blockIdx.z;
  const int t  = threadIdx.x;

  const int l  = t & 63;
  const int w  = t >> 6;
  const int lr = l & 15;
  const int lk = l >> 4;
  const int lk16 = lk * 16;
  const int wr = (w >> 1) * 64;
  const int wc = (w & 1) * 64;

  const int n0 = nx * 128;
  const char* VTb = (const char*)(VT + (size_t)b * DIM * SEQ) + (size_t)n0 * 8192;
  const unsigned short* Spb = Sp + (size_t)b * TRI * 16384;

  for (int half = 0; half < 2; ++half){
    const int ti = half ? pr : (31 - pr);
    const int m0 = ti * 128;
    const char* Pt = (const char*)(Spb + (size_t)(ti * (ti + 1) / 2) * 16384);
    const int ksteps = 2 * (ti + 1);

    f32x4 acc[4][4];
    #pragma unroll
    for (int i = 0; i < 4; ++i)
      #pragma unroll
      for (int j = 0; j < 4; ++j) acc[i][j] = (f32x4)0.0f;

    for (int s = 0; s < ksteps; ++s){
      STAGE_AB(Pt + (size_t)(s >> 1) * 32768 + (s & 1) * 128, 256,
               VTb + s * 128, 8192);
      WAITVM0;
      __syncthreads();
      COMPUTE128S();
      __syncthreads();
    }

    const float* lb = lrow + (size_t)b * SEQ + m0;
    float* ob = out + ((size_t)b * SEQ + m0) * DIM + n0;
    #pragma unroll
    for (int i = 0; i < 4; ++i)
      #pragma unroll
      for (int r = 0; r < 4; ++r){
        int row = wr + i*16 + lk*4 + r;
        float inv = 1.0f / lb[row];
        #pragma unroll
        for (int j = 0; j < 4; ++j)
          ob[(size_t)row * DIM + wc + j*16 + lr] = acc[i][j][r] * inv;
      }
  }
}

// ---------------- launch ----------------
extern "C" void kernel_launch(void* const* d_in, const int* in_sizes, int n_in,
                              void* d_out, int out_size, void* d_ws, size_t ws_size,
                              hipStream_t stream)
{
  (void)in_sizes; (void)n_in; (void)out_size; (void)ws_size;
  const float* emb = (const float*)d_in[0];
  const float* Wq  = (const float*)d_in[1];
  const float* Wk  = (const float*)d_in[2];
  const float* Wv  = (const float*)d_in[3];

  char* ws = (char*)d_ws;
  unsigned short* EB = (unsigned short*)ws;                    // 32MB (reused as VT)
  unsigned short* WB = (unsigned short*)(ws + 33554432);       // 6MB: Wq|Wk|Wv bf16
  unsigned short* Qb = (unsigned short*)(ws + 39845888);       // 32MB
  unsigned short* Kb = (unsigned short*)(ws + 73400320);       // 32MB
  unsigned short* Sp = (unsigned short*)(ws + 106954752);      // 66MB packed P tiles
  float*          lr = (float*)(ws + 176160768);               // 64KB row sums
  unsigned short* Vb = (unsigned short*)d_out;                 // V scratch in out buffer
  unsigned short* VT = EB;                                     // alias: E dead after gemm

  hipMemsetAsync(lr, 0, (size_t)NB * SEQ * sizeof(float), stream);

  cvt_kernel<<<16384, 256, 0, stream>>>(emb, EB, 4194304);
  cvt_kernel<<<1024, 256, 0, stream>>>(Wq, WB,           262144);
  cvt_kernel<<<1024, 256, 0, stream>>>(Wk, WB + 1048576, 262144);
  cvt_kernel<<<1024, 256, 0, stream>>>(Wv, WB + 2097152, 262144);

  gemm_qkv<<<dim3(8, 128, 3), 256, 0, stream>>>(EB, WB, Qb, Kb, Vb);
  transpose_v<<<dim3(64, 16, 4), 256, 0, stream>>>(Vb, VT);

  sp_gemm<<<dim3(32, 32, 4), 256, 0, stream>>>(Qb, Kb, Sp, lr);
  pv_gemm<<<dim3(8, 16, 4), 256, 0, stream>>>(Sp, VT, lr, (float*)d_out);
}